// Round 8
// baseline (332.603 us; speedup 1.0000x reference)
//
#include <hip/hip_runtime.h>
#include <hip/hip_bf16.h>

typedef __bf16 bf16;
typedef __bf16 bf16x4 __attribute__((ext_vector_type(4)));
typedef __bf16 bf16x8 __attribute__((ext_vector_type(8)));
typedef float  f32x4  __attribute__((ext_vector_type(4)));

#define T_SZ   4096
#define NFREQ  512
#define HOP    512
#define OUT_LEN 2097664   // 4097 * 512
#define NTT33  33
#define XROWS  4097       // phys rows per batch in Xw: row r holds t = r-1 (row 0 = zeros)

#define XW_ELEMS ((size_t)16 * XROWS * 1024)
#define WT_ELEMS ((size_t)1024 * 1024)   // over-alloc (Wt2 needs 512*1024)
#define WS_NEED  ((XW_ELEMS + WT_ELEMS) * 2)

__device__ __forceinline__ void gl16(const void* g, void* l) {
    __builtin_amdgcn_global_load_lds(
        (const __attribute__((address_space(1))) void*)g,
        (__attribute__((address_space(3))) void*)l, 16, 0, 0);
}

// k-permutation: p<256: rk/m at c=2p | p in [256,512): ik/phase at c=2(p-256)
//              | p in [512,768): rk/m at c=2(p-512)+1 | p>=768: ik/phase at odd c.
// Symmetry used: W[j+512, c] = (-1)^(c+1) W[j, c]  ->  frame[j]=E+O, frame[j+512]=O-E
// with E = sum over even c (k-half 0), O = sum over odd c (k-half 1).

// ---------- Wt2[j][p], j in [0,512); blocks<16 also zero Xw2 row 0 ----------
__global__ __launch_bounds__(256, 4) void cvt_w(const float* __restrict__ rk,
                                                const float* __restrict__ ik,
                                                bf16* __restrict__ Wt2,
                                                bf16* __restrict__ Xw) {
    const int j   = blockIdx.x;          // 512
    const int p4  = threadIdx.x * 4;
    const int reg = p4 >> 8;
    const int idx = p4 & 255;
    const int c0  = 2 * idx + (reg >> 1);
    const float* s = ((reg & 1) ? ik : rk) + (size_t)j * NFREQ;
    bf16x4 h;
    h[0] = (bf16)s[c0];     h[1] = (bf16)s[c0 + 2];
    h[2] = (bf16)s[c0 + 4]; h[3] = (bf16)s[c0 + 6];
    *(bf16x4*)&Wt2[((size_t)j << 10) + p4] = h;
    if (j < 16) {   // zero phys row 0 of batch j (t = -1)
        bf16x4 z = {};
        *(bf16x4*)&Xw[(((size_t)j * XROWS) << 10) + p4] = z;
    }
}

// ---------- Xw[b][1+t][p] = permuted (magn|phase)[b][c(p)][t] ----------
__global__ __launch_bounds__(256, 4) void cvt_x(const float* __restrict__ magn,
                                                const float* __restrict__ phase,
                                                bf16* __restrict__ Xw) {
    __shared__ bf16 t2[64][132];
    const int tid = threadIdx.x;
    const int bid = blockIdx.x;
    const int kt  = bid & 15;            // dest p-tile of 64
    const int tt  = (bid >> 4) & 31;     // t-tile of 128
    const int b   = bid >> 9;
    const int reg = kt >> 2;             // 0 m-even, 1 phi-even, 2 m-odd, 3 phi-odd
    const int c0  = 128 * (kt & 3) + (reg >> 1);
    const float* srcb = ((reg & 1) ? phase : magn) + (size_t)b * NFREQ * T_SZ + (size_t)tt * 128;
    const int fr = tid >> 5;
    const int c  = (tid & 31) * 4;
    #pragma unroll
    for (int p = 0; p < 8; ++p) {
        const int f = c0 + 2 * (fr + 8 * p);         // source row (stride-2 in c)
        f32x4 v = *(const f32x4*)&srcb[(size_t)f * T_SZ + c];
        bf16x4 h;
        h[0] = (bf16)v[0]; h[1] = (bf16)v[1]; h[2] = (bf16)v[2]; h[3] = (bf16)v[3];
        *(bf16x4*)&t2[fr + 8 * p][c] = h;
    }
    __syncthreads();
    const int koff = (tid & 7) * 8;
    bf16* dstb = Xw + (((size_t)b * XROWS + 1 + tt * 128) << 10) + kt * 64 + koff;
    #pragma unroll
    for (int q = 0; q < 4; ++q) {
        const int tr = (tid >> 3) + 32 * q;
        bf16x8 o;
        #pragma unroll
        for (int ki = 0; ki < 8; ++ki) o[ki] = t2[koff + ki][tr];
        *(bf16x8*)&dstb[(size_t)tr << 10] = o;
    }
}

// ---------- main GEMM: 128j x 64t tile, 4 waves, parity-symmetric (half FLOPs) ----------
// A-tile: 128 rows = Wt2[j0+r]. B-tile row r (0..64) = X[t0-1+r] (phys Xw row t0+r).
// K-steps 0..15 accumulate E planes (even c), 16..31 accumulate O planes (odd c).
// out[tt*512+jl] = (E_t + O_t - E_t1 + O_t1 + ac[tt] + ac[tt-1]) / 1024.
// Swizzle both-sides: 16B slot' = slot ^ ((row ^ row>>2)&3).
__global__ __launch_bounds__(256, 3) void istft_gemm5(
    const bf16* __restrict__ Xw, const bf16* __restrict__ Wt2,
    const float* __restrict__ acv, float* __restrict__ out)
{
    __shared__ __attribute__((aligned(16))) bf16 As[2][128 * 32];
    __shared__ __attribute__((aligned(16))) bf16 Bs[2][65 * 32];

    const int tid = threadIdx.x;
    const int w   = tid >> 6;      // 4 waves: wr = w>>1 (j half of 64), wc = w&1 (t half of 32)
    const int l   = tid & 63;

    const int bid = blockIdx.x;    // 4096 = 512 pg x 8; panel = (b, t-tile), 4 j-blocks/panel
    const int xcd = bid & 7;
    const int jt  = (bid >> 3) & 3;
    const int pg  = bid >> 5;      // 0..127
    const int pnl = pg * 8 + xcd;  // 0..1023
    const int b   = pnl >> 6;
    const int tt0 = pnl & 63;
    const int j0  = jt * 128;
    const int t0  = tt0 * 64;
    const size_t xb = (size_t)b * XROWS;

    // staging map: 64B rows of 4 slots; lane -> row (l>>2), slot l&3, pre-swizzled source slot
    const int ssrc = ((l & 3) ^ ((l >> 2) & 3) ^ ((l >> 4) & 3)) * 8;
    const int arow = 16 * w + (l >> 2);                 // 0..63 per sweep

    const size_t agj0 = ((size_t)(j0 + arow)) << 10;        // A rows 0..63
    const size_t agj1 = ((size_t)(j0 + 64 + arow)) << 10;   // A rows 64..127
    const size_t bsrc  = (xb + t0 + arow) << 10;            // B rows 0..63
    const size_t bsrcX = (xb + t0 + 64) << 10;              // B row 64 (g(64)=0: linear)

    auto stage = [&](int p, int ks) {
        const int k0 = ks * 32;
        gl16(Wt2 + agj0 + k0 + ssrc, &As[p][(16 * w) * 32]);
        gl16(Wt2 + agj1 + k0 + ssrc, &As[p][(64 + 16 * w) * 32]);
        gl16(Xw + bsrc + k0 + ssrc, &Bs[p][(16 * w) * 32]);
        if (l < 4) gl16(Xw + bsrcX + k0 + l * 8, &Bs[p][64 * 32]);
    };

    f32x4 et[4][2], et1[4][2], ot[4][2], ot1[4][2];
    #pragma unroll
    for (int m = 0; m < 4; ++m)
        #pragma unroll
        for (int n = 0; n < 2; ++n) {
            et[m][n] = (f32x4){0.f, 0.f, 0.f, 0.f};
            et1[m][n] = (f32x4){0.f, 0.f, 0.f, 0.f};
            ot[m][n] = (f32x4){0.f, 0.f, 0.f, 0.f};
            ot1[m][n] = (f32x4){0.f, 0.f, 0.f, 0.f};
        }

    const int wr = w >> 1, wc = w & 1;
    const int c15 = l & 15, c4 = l >> 4;

    bf16x8 a[4], bl[2], bh[2];
    auto rdFrags = [&](int p) {
        #pragma unroll
        for (int m = 0; m < 4; ++m) {
            const int r = wr * 64 + m * 16 + c15;            // 0..127
            const int s = ((c4 ^ r ^ (r >> 2)) & 3) * 8;
            a[m] = *(const bf16x8*)&As[p][r * 32 + s];
        }
        #pragma unroll
        for (int n = 0; n < 2; ++n) {
            const int rH = wc * 32 + n * 16 + c15;           // 0..63 (t = tt-1)
            const int sH = ((c4 ^ rH ^ (rH >> 2)) & 3) * 8;
            bh[n] = *(const bf16x8*)&Bs[p][rH * 32 + sH];
            const int rL = rH + 1;                           // 1..64 (t = tt)
            const int sL = ((c4 ^ rL ^ (rL >> 2)) & 3) * 8;
            bl[n] = *(const bf16x8*)&Bs[p][rL * 32 + sL];
        }
    };

    stage(0, 0);
    __syncthreads();

    // even-c half -> E planes
    for (int ks = 0; ks < 16; ++ks) {
        const int P = ks & 1;
        stage(P ^ 1, ks + 1);
        rdFrags(P);
        #pragma unroll
        for (int m = 0; m < 4; ++m)
            #pragma unroll
            for (int n = 0; n < 2; ++n) {
                et[m][n]  = __builtin_amdgcn_mfma_f32_16x16x32_bf16(a[m], bl[n], et[m][n], 0, 0, 0);
                et1[m][n] = __builtin_amdgcn_mfma_f32_16x16x32_bf16(a[m], bh[n], et1[m][n], 0, 0, 0);
            }
        __syncthreads();
    }
    // odd-c half -> O planes
    for (int ks = 16; ks < 32; ++ks) {
        const int P = ks & 1;
        if (ks + 1 < 32) stage(P ^ 1, ks + 1);
        rdFrags(P);
        #pragma unroll
        for (int m = 0; m < 4; ++m)
            #pragma unroll
            for (int n = 0; n < 2; ++n) {
                ot[m][n]  = __builtin_amdgcn_mfma_f32_16x16x32_bf16(a[m], bl[n], ot[m][n], 0, 0, 0);
                ot1[m][n] = __builtin_amdgcn_mfma_f32_16x16x32_bf16(a[m], bh[n], ot1[m][n], 0, 0, 0);
            }
        __syncthreads();
    }

    // epilogue: out[tt*512+jl] = (E_t + O_t - E_t1 + O_t1 + ac[tt] + ac[tt-1]) / 1024
    const float inv = 1.0f / 1024.0f;
    float* ob = out + (size_t)b * OUT_LEN;
    const float* acb = acv + (size_t)b * T_SZ;
    const int jbase = j0 + wr * 64 + c4 * 4;
    #pragma unroll
    for (int n = 0; n < 2; ++n) {
        const int tt = t0 + wc * 32 + n * 16 + c15;          // 0..4095
        const float acs = acb[tt] + (tt ? acb[tt - 1] : 0.f);
        #pragma unroll
        for (int m = 0; m < 4; ++m) {
            f32x4 v;
            #pragma unroll
            for (int rr = 0; rr < 4; ++rr)
                v[rr] = (et[m][n][rr] + ot[m][n][rr] - et1[m][n][rr] + ot1[m][n][rr] + acs) * inv;
            __builtin_nontemporal_store(v, (f32x4*)&ob[(size_t)tt * HOP + jbase + m * 16]);
        }
    }
}

// ---------- tail: out column t=4096 = frame[4095, n+512] + ac = (O - E)(t=4095) ----------
__global__ __launch_bounds__(256, 2) void istft_tail(
    const bf16* __restrict__ Xw, const bf16* __restrict__ Wt2,
    const float* __restrict__ acv, float* __restrict__ out)
{
    __shared__ float xf[1024];
    const int b = blockIdx.x, tid = threadIdx.x;
    const bf16* xr = Xw + (((size_t)b * XROWS + 4096) << 10);   // t = 4095, k-permuted
    {
        bf16x4 v = *(const bf16x4*)&xr[tid * 4];
        xf[tid * 4 + 0] = (float)v[0]; xf[tid * 4 + 1] = (float)v[1];
        xf[tid * 4 + 2] = (float)v[2]; xf[tid * 4 + 3] = (float)v[3];
    }
    __syncthreads();
    const float acs = acv[b * T_SZ + 4095];
    float s0 = 0.f, s1 = 0.f;
    const bf16* w0 = Wt2 + ((size_t)tid << 10);
    const bf16* w1 = Wt2 + ((size_t)(tid + 256) << 10);
    for (int kc = 0; kc < 128; ++kc) {
        const float sgn = (kc < 64) ? -1.f : 1.f;   // E half negated, O half added
        bf16x8 av = *(const bf16x8*)&w0[kc * 8];
        bf16x8 cv = *(const bf16x8*)&w1[kc * 8];
        float t0a = 0.f, t1a = 0.f;
        #pragma unroll
        for (int e = 0; e < 8; ++e) {
            const float xv = xf[kc * 8 + e];
            t0a += xv * (float)av[e];
            t1a += xv * (float)cv[e];
        }
        s0 += sgn * t0a; s1 += sgn * t1a;
    }
    float* ob = out + (size_t)b * OUT_LEN + (size_t)4096 * HOP;
    ob[tid]       = (s0 + acs) * (1.f / 1024.f);
    ob[tid + 256] = (s1 + acs) * (1.f / 1024.f);
}

// ---------- fallback (round-2 kernel, no workspace needed) ----------
#define LDBL 40
__global__ __launch_bounds__(256, 2) void istft_fused_legacy(
    const float* __restrict__ magn, const float* __restrict__ phase,
    const float* __restrict__ acv,
    const float* __restrict__ rk,  const float* __restrict__ ik,
    float* __restrict__ out)
{
    __shared__ __attribute__((aligned(16))) bf16 As[2][128 * LDBL];
    __shared__ __attribute__((aligned(16))) bf16 Bs[2][129 * LDBL];
    const int tid = threadIdx.x;
    const int w = tid >> 6, l = tid & 63;
    const int bid = blockIdx.x;
    const int xcd = bid & 7, q = bid >> 3;
    const int jt = q & 7, pgrp = q >> 3;
    const int pnl = pgrp * 8 + xcd;
    const int b = pnl / NTT33, tt0 = pnl - b * NTT33;
    const int j0 = jt * 64, t0 = tt0 * 128;
    const float* xm = magn  + (size_t)b * NFREQ * T_SZ;
    const float* xp = phase + (size_t)b * NFREQ * T_SZ;
    const int jrow = tid >> 3, fc = (tid & 7) * 4;
    const int f0 = (tid >> 5) * 4, tl = tid & 31;
    f32x4 areg[4]; float vreg[4][4]; float rz = 0.f;
    f32x4 acc[8][2];
    #pragma unroll
    for (int i = 0; i < 8; ++i)
        #pragma unroll
        for (int j = 0; j < 2; ++j) acc[i][j] = (f32x4){0.f, 0.f, 0.f, 0.f};
    const int nbase = w * 32;
    auto loadA = [&](int ks) {
        const int k0 = ks * 32;
        const float* wsrc = (k0 < NFREQ) ? (rk + k0) : (ik + (k0 - NFREQ));
        #pragma unroll
        for (int i = 0; i < 4; ++i) {
            const int jr = jrow + 32 * i;
            const int j = (jr < 64) ? (j0 + jr) : (j0 + 448 + jr);
            areg[i] = *(const f32x4*)&wsrc[(size_t)j * NFREQ + fc];
        }
    };
    auto writeA = [&](int p) {
        #pragma unroll
        for (int i = 0; i < 4; ++i) {
            bf16x4 v;
            v[0] = (bf16)areg[i][0]; v[1] = (bf16)areg[i][1];
            v[2] = (bf16)areg[i][2]; v[3] = (bf16)areg[i][3];
            *(bf16x4*)&As[p][(jrow + 32 * i) * LDBL + fc] = v;
        }
    };
    auto loadB = [&](int ks) {
        const int k0 = ks * 32;
        const float* xbp = (k0 < NFREQ) ? (xm + (size_t)k0 * T_SZ)
                                        : (xp + (size_t)(k0 - NFREQ) * T_SZ);
        #pragma unroll
        for (int i = 0; i < 4; ++i) {
            if (t0 + 32 * i + 32 <= T_SZ) {
                #pragma unroll
                for (int fj = 0; fj < 4; ++fj)
                    vreg[fj][i] = xbp[(size_t)(f0 + fj) * T_SZ + t0 + tl + 32 * i];
            } else {
                #pragma unroll
                for (int fj = 0; fj < 4; ++fj) vreg[fj][i] = 0.f;
            }
        }
        if (tid < 32) rz = (t0 >= 1) ? xbp[(size_t)tid * T_SZ + (t0 - 1)] : 0.f;
    };
    auto writeB = [&](int p) {
        #pragma unroll
        for (int i = 0; i < 4; ++i) {
            bf16x4 v;
            v[0] = (bf16)vreg[0][i]; v[1] = (bf16)vreg[1][i];
            v[2] = (bf16)vreg[2][i]; v[3] = (bf16)vreg[3][i];
            *(bf16x4*)&Bs[p][(1 + tl + 32 * i) * LDBL + f0] = v;
        }
        if (tid < 32) Bs[p][tid] = (bf16)rz;
    };
    loadA(0); loadB(0); writeA(0); writeB(0);
    __syncthreads();
    int p = 0;
    for (int ks = 0; ks < 32; ++ks) {
        if (ks + 1 < 32) { loadA(ks + 1); loadB(ks + 1); }
        bf16x8 af[8], blv[2], bhv[2];
        #pragma unroll
        for (int mi = 0; mi < 8; ++mi)
            af[mi] = *(const bf16x8*)&As[p][(mi * 16 + (l & 15)) * LDBL + (l >> 4) * 8];
        #pragma unroll
        for (int ni = 0; ni < 2; ++ni) {
            const int rb = nbase + ni * 16 + (l & 15);
            bhv[ni] = *(const bf16x8*)&Bs[p][rb * LDBL + (l >> 4) * 8];
            blv[ni] = *(const bf16x8*)&Bs[p][(rb + 1) * LDBL + (l >> 4) * 8];
        }
        #pragma unroll
        for (int ni = 0; ni < 2; ++ni)
            #pragma unroll
            for (int mi = 0; mi < 4; ++mi) {
                acc[mi][ni] = __builtin_amdgcn_mfma_f32_16x16x32_bf16(af[mi], blv[ni], acc[mi][ni], 0, 0, 0);
                acc[mi + 4][ni] = __builtin_amdgcn_mfma_f32_16x16x32_bf16(af[mi + 4], bhv[ni], acc[mi + 4][ni], 0, 0, 0);
            }
        if (ks + 1 < 32) { writeA(p ^ 1); writeB(p ^ 1); }
        __syncthreads();
        p ^= 1;
    }
    const float inv = 1.0f / 1024.0f;
    float* ob = out + (size_t)b * OUT_LEN;
    const float* acb = acv + (size_t)b * T_SZ;
    #pragma unroll
    for (int ni = 0; ni < 2; ++ni) {
        const int tt = t0 + nbase + ni * 16 + (l & 15);
        if (tt <= T_SZ) {
            float acs = 0.f;
            if (tt < T_SZ) acs += acb[tt];
            if (tt >= 1)   acs += acb[tt - 1];
            #pragma unroll
            for (int mi = 0; mi < 4; ++mi) {
                const int jl = j0 + mi * 16 + (l >> 4) * 4;
                f32x4 v;
                #pragma unroll
                for (int rr = 0; rr < 4; ++rr)
                    v[rr] = (acc[mi][ni][rr] + acc[mi + 4][ni][rr] + acs) * inv;
                __builtin_nontemporal_store(v, (f32x4*)&ob[(size_t)tt * HOP + jl]);
            }
        }
    }
}

extern "C" void kernel_launch(void* const* d_in, const int* in_sizes, int n_in,
                              void* d_out, int out_size, void* d_ws, size_t ws_size,
                              hipStream_t stream) {
    const float* magn  = (const float*)d_in[0];
    const float* phase = (const float*)d_in[1];
    const float* ac    = (const float*)d_in[2];
    const float* rk    = (const float*)d_in[3];
    const float* ik    = (const float*)d_in[4];
    float* out = (float*)d_out;

    if (ws_size >= WS_NEED) {
        bf16* Xw  = (bf16*)d_ws;
        bf16* Wt2 = Xw + XW_ELEMS;
        cvt_w<<<512, 256, 0, stream>>>(rk, ik, Wt2, Xw);
        cvt_x<<<8192, 256, 0, stream>>>(magn, phase, Xw);
        istft_gemm5<<<4096, 256, 0, stream>>>(Xw, Wt2, ac, out);
        istft_tail<<<16, 256, 0, stream>>>(Xw, Wt2, ac, out);
    } else {
        istft_fused_legacy<<<528 * 8, 256, 0, stream>>>(magn, phase, ac, rk, ik, out);
    }
}

// Round 9
// 179.278 us; speedup vs baseline: 1.8552x; 1.8552x over previous
//
#include <hip/hip_runtime.h>
#include <hip/hip_bf16.h>

typedef __bf16 bf16;
typedef __bf16 bf16x4 __attribute__((ext_vector_type(4)));
typedef __bf16 bf16x8 __attribute__((ext_vector_type(8)));
typedef float  f32x4  __attribute__((ext_vector_type(4)));

#define T_SZ   4096
#define NFREQ  512
#define HOP    512
#define OUT_LEN 2097664   // 4097 * 512
#define NTT33  33
#define XROWS  4097       // Xw row t holds Y[:,t], t in [0,4096]

#define XW_ELEMS ((size_t)16 * XROWS * 1024)
#define WT_ELEMS ((size_t)512 * 1024)
#define WS_NEED  ((XW_ELEMS + WT_ELEMS) * 2)

__device__ __forceinline__ void gl16(const void* g, void* l) {
    __builtin_amdgcn_global_load_lds(
        (const __attribute__((address_space(1))) void*)g,
        (__attribute__((address_space(3))) void*)l, 16, 0, 0);
}

// Symmetry: W[j+512,c] = (-1)^(c+1) W[j,c].  With Y[k,t] = x[k,t] + s_k x[k,t-1],
// s_k = (c odd ? +1 : -1), c = k mod 512:  out[t*512+j] = (W[j,:]·Y[:,t] + ac[t] + ac[t-1])/1024.
// Single 512x1024 GEMM — half the FLOPs of the lo/hi formulation.

// ---------- Wt[j][k] = k<512 ? rk[j][k] : ik[j][k-512], j in [0,512) ----------
__global__ __launch_bounds__(256, 4) void cvt_w(const float* __restrict__ rk,
                                                const float* __restrict__ ik,
                                                bf16* __restrict__ Wt) {
    const int j  = blockIdx.x;           // 512
    const int k4 = threadIdx.x * 4;
    const float* s = (k4 < NFREQ) ? &rk[j * NFREQ + k4] : &ik[j * NFREQ + k4 - NFREQ];
    f32x4 v = *(const f32x4*)s;
    bf16x4 h;
    h[0] = (bf16)v[0]; h[1] = (bf16)v[1]; h[2] = (bf16)v[2]; h[3] = (bf16)v[3];
    *(bf16x4*)&Wt[((size_t)j << 10) + k4] = h;
}

// ---------- Xw[b][t][k] = Y[k,t]  (transpose + bf16 + the s_k combine) ----------
__global__ __launch_bounds__(256, 4) void cvt_x(const float* __restrict__ magn,
                                                const float* __restrict__ phase,
                                                bf16* __restrict__ Xw) {
    __shared__ float t2[64][133];        // cols 0..127 = x[t0..t0+127], col 128 = x[t0-1]
    const int tid = threadIdx.x;
    const int bid = blockIdx.x;
    const int kt  = bid & 15;            // k-tile of 64 (global k = kt*64 + f)
    const int tt  = (bid >> 4) & 31;     // t-tile of 128
    const int b   = bid >> 9;
    const float* srcb = (kt < 8 ? magn : phase)
                      + ((size_t)b * NFREQ + (kt & 7) * 64) * T_SZ + tt * 128;
    const int fr = tid >> 5;
    const int cc = (tid & 31) * 4;
    #pragma unroll
    for (int p = 0; p < 8; ++p) {
        const int f = fr + 8 * p;
        f32x4 v = *(const f32x4*)&srcb[(size_t)f * T_SZ + cc];
        t2[f][cc + 0] = v[0]; t2[f][cc + 1] = v[1];
        t2[f][cc + 2] = v[2]; t2[f][cc + 3] = v[3];
    }
    if (tid < 64)
        t2[tid][128] = (tt > 0) ? srcb[(size_t)tid * T_SZ - 1] : 0.f;
    __syncthreads();

    const int koff = (tid & 7) * 8;      // local k base (lanes 0..7 -> 128B contiguous)
    bf16* dstb = Xw + (((size_t)b * XROWS + tt * 128) << 10) + kt * 64 + koff;
    #pragma unroll
    for (int q = 0; q < 4; ++q) {
        const int tr  = (tid >> 3) + 32 * q;
        const int im1 = tr ? (tr - 1) : 128;
        bf16x8 o;
        #pragma unroll
        for (int ki = 0; ki < 8; ++ki) {
            const int f = koff + ki;
            const float sgn = (f & 1) ? 1.f : -1.f;   // c parity == f parity
            o[ki] = (bf16)(t2[f][tr] + sgn * t2[f][im1]);
        }
        *(bf16x8*)&dstb[(size_t)tr << 10] = o;
    }
    // row t = 4096: Y = s_k * x[k, 4095]  (x[:,4096] = 0)
    if (tt == 31 && tid < 8) {
        bf16x8 o;
        #pragma unroll
        for (int ki = 0; ki < 8; ++ki) {
            const int f = tid * 8 + ki;
            const float sgn = (f & 1) ? 1.f : -1.f;
            o[ki] = (bf16)(sgn * t2[f][127]);
        }
        *(bf16x8*)&Xw[(((size_t)b * XROWS + 4096) << 10) + kt * 64 + tid * 8] = o;
    }
}

// ---------- main GEMM: 128j x 256t tile, 8 waves, 2-barrier loop, half-FLOP Y form ----------
// A-tile: 128 rows = Wt[j0+r], r<128, j0 in {0,128,256,384}.  B-tile row r = Y[:, t0+r],
// r in [0,256), source row clamped to 4096 (garbage cols masked at store).
// Swizzle both-sides: 16B slot' = slot ^ ((row ^ row>>2)&3); LDS linear dest,
// gl16 SOURCE pre-swizzled, ds_read applies the same XOR.
__global__ __launch_bounds__(512, 4) void istft_gemmY(
    const bf16* __restrict__ Xw, const bf16* __restrict__ Wt,
    const float* __restrict__ acv, float* __restrict__ out)
{
    __shared__ __attribute__((aligned(16))) bf16 As[2][128 * 32];
    __shared__ __attribute__((aligned(16))) bf16 Bs[2][256 * 32];

    const int tid = threadIdx.x;
    const int w   = tid >> 6;      // 8 waves: wr = w>>2 (j half of 64), wc = w&3 (t quarter of 64)
    const int l   = tid & 63;
    const int wr  = w >> 2, wc = w & 3;
    const int c15 = l & 15, c4 = l >> 4;

    const int bid = blockIdx.x;    // 1088 = 272 panels x 4 j-tiles; panel -> xcd = bid&7
    const int xcd = bid & 7;
    const int jt  = (bid >> 3) & 3;
    const int pg  = bid >> 5;      // 0..33
    const int pnl = pg * 8 + xcd;  // 0..271 (16 b x 17 t-tiles)
    const int b   = pnl / 17;
    const int tt0 = pnl - b * 17;
    const int j0  = jt * 128;
    const int t0  = tt0 * 256;     // t0 <= 4096
    const size_t xb = (size_t)b * XROWS;

    // staging: wave w covers rows 16w..16w+15 per sweep; lane l -> row 16w+(l>>2), slot l&3
    const int ssrc = ((l & 3) ^ ((l >> 2) & 3) ^ ((l >> 4) & 3)) * 8;  // pre-swizzled src slot
    const int srow = 16 * w + (l >> 2);                                // 0..127
    const size_t asrc = ((size_t)(j0 + srow)) << 10;
    int tq0 = t0 + srow;        if (tq0 > 4096) tq0 = 4096;            // clamp (tile 16 only)
    int tq1 = t0 + 128 + srow;  if (tq1 > 4096) tq1 = 4096;
    const size_t bsrc0 = (xb + tq0) << 10;
    const size_t bsrc1 = (xb + tq1) << 10;

    auto stage = [&](int p, int ks) {
        const int k0 = ks * 32;
        gl16(Wt + asrc + k0 + ssrc, &As[p][(16 * w) * 32]);
        gl16(Xw + bsrc0 + k0 + ssrc, &Bs[p][(16 * w) * 32]);
        gl16(Xw + bsrc1 + k0 + ssrc, &Bs[p][(128 + 16 * w) * 32]);
    };

    f32x4 acc[4][4];
    #pragma unroll
    for (int i = 0; i < 4; ++i)
        #pragma unroll
        for (int j = 0; j < 4; ++j)
            acc[i][j] = (f32x4){0.f, 0.f, 0.f, 0.f};

    bf16x8 a[4], bb[4];
    auto rdFrags = [&](int p) {
        #pragma unroll
        for (int m = 0; m < 4; ++m) {
            const int r = wr * 64 + m * 16 + c15;            // 0..127
            const int s = ((c4 ^ r ^ (r >> 2)) & 3) * 8;
            a[m] = *(const bf16x8*)&As[p][r * 32 + s];
        }
        #pragma unroll
        for (int n = 0; n < 4; ++n) {
            const int r = wc * 64 + n * 16 + c15;            // 0..255
            const int s = ((c4 ^ r ^ (r >> 2)) & 3) * 8;
            bb[n] = *(const bf16x8*)&Bs[p][r * 32 + s];
        }
    };

    stage(0, 0);
    __syncthreads();

    for (int ks = 0; ks < 32; ++ks) {
        const int P = ks & 1;
        if (ks + 1 < 32) stage(P ^ 1, ks + 1);   // issue next-tile loads first
        rdFrags(P);
        #pragma unroll
        for (int m = 0; m < 4; ++m)
            #pragma unroll
            for (int n = 0; n < 4; ++n)
                acc[m][n] = __builtin_amdgcn_mfma_f32_16x16x32_bf16(
                    a[m], bb[n], acc[m][n], 0, 0, 0);
        __syncthreads();   // drains staging loads; hidden by co-resident blocks
    }

    // epilogue: out[tt*512+j] = (acc + ac[tt] + ac[tt-1]) / 1024, masked at tt>4096
    const float inv = 1.0f / 1024.0f;
    float* ob = out + (size_t)b * OUT_LEN;
    const float* acb = acv + (size_t)b * T_SZ;
    const int jbase = j0 + wr * 64 + c4 * 4;
    #pragma unroll
    for (int n = 0; n < 4; ++n) {
        const int tt = t0 + wc * 64 + n * 16 + c15;          // 0..4351
        if (tt <= 4096) {
            const float acs = (tt < T_SZ ? acb[tt] : 0.f) + (tt ? acb[tt - 1] : 0.f);
            #pragma unroll
            for (int m = 0; m < 4; ++m) {
                f32x4 v;
                #pragma unroll
                for (int rr = 0; rr < 4; ++rr)
                    v[rr] = (acc[m][n][rr] + acs) * inv;
                __builtin_nontemporal_store(v, (f32x4*)&ob[(size_t)tt * HOP + jbase + m * 16]);
            }
        }
    }
}

// ---------- fallback (round-2 kernel, no workspace needed) ----------
#define LDBL 40
__global__ __launch_bounds__(256, 2) void istft_fused_legacy(
    const float* __restrict__ magn, const float* __restrict__ phase,
    const float* __restrict__ acv,
    const float* __restrict__ rk,  const float* __restrict__ ik,
    float* __restrict__ out)
{
    __shared__ __attribute__((aligned(16))) bf16 As[2][128 * LDBL];
    __shared__ __attribute__((aligned(16))) bf16 Bs[2][129 * LDBL];
    const int tid = threadIdx.x;
    const int w = tid >> 6, l = tid & 63;
    const int bid = blockIdx.x;
    const int xcd = bid & 7, q = bid >> 3;
    const int jt = q & 7, pgrp = q >> 3;
    const int pnl = pgrp * 8 + xcd;
    const int b = pnl / NTT33, tt0 = pnl - b * NTT33;
    const int j0 = jt * 64, t0 = tt0 * 128;
    const float* xm = magn  + (size_t)b * NFREQ * T_SZ;
    const float* xp = phase + (size_t)b * NFREQ * T_SZ;
    const int jrow = tid >> 3, fc = (tid & 7) * 4;
    const int f0 = (tid >> 5) * 4, tl = tid & 31;
    f32x4 areg[4]; float vreg[4][4]; float rz = 0.f;
    f32x4 acc[8][2];
    #pragma unroll
    for (int i = 0; i < 8; ++i)
        #pragma unroll
        for (int j = 0; j < 2; ++j) acc[i][j] = (f32x4){0.f, 0.f, 0.f, 0.f};
    const int nbase = w * 32;
    auto loadA = [&](int ks) {
        const int k0 = ks * 32;
        const float* wsrc = (k0 < NFREQ) ? (rk + k0) : (ik + (k0 - NFREQ));
        #pragma unroll
        for (int i = 0; i < 4; ++i) {
            const int jr = jrow + 32 * i;
            const int j = (jr < 64) ? (j0 + jr) : (j0 + 448 + jr);
            areg[i] = *(const f32x4*)&wsrc[(size_t)j * NFREQ + fc];
        }
    };
    auto writeA = [&](int p) {
        #pragma unroll
        for (int i = 0; i < 4; ++i) {
            bf16x4 v;
            v[0] = (bf16)areg[i][0]; v[1] = (bf16)areg[i][1];
            v[2] = (bf16)areg[i][2]; v[3] = (bf16)areg[i][3];
            *(bf16x4*)&As[p][(jrow + 32 * i) * LDBL + fc] = v;
        }
    };
    auto loadB = [&](int ks) {
        const int k0 = ks * 32;
        const float* xbp = (k0 < NFREQ) ? (xm + (size_t)k0 * T_SZ)
                                        : (xp + (size_t)(k0 - NFREQ) * T_SZ);
        #pragma unroll
        for (int i = 0; i < 4; ++i) {
            if (t0 + 32 * i + 32 <= T_SZ) {
                #pragma unroll
                for (int fj = 0; fj < 4; ++fj)
                    vreg[fj][i] = xbp[(size_t)(f0 + fj) * T_SZ + t0 + tl + 32 * i];
            } else {
                #pragma unroll
                for (int fj = 0; fj < 4; ++fj) vreg[fj][i] = 0.f;
            }
        }
        if (tid < 32) rz = (t0 >= 1) ? xbp[(size_t)tid * T_SZ + (t0 - 1)] : 0.f;
    };
    auto writeB = [&](int p) {
        #pragma unroll
        for (int i = 0; i < 4; ++i) {
            bf16x4 v;
            v[0] = (bf16)vreg[0][i]; v[1] = (bf16)vreg[1][i];
            v[2] = (bf16)vreg[2][i]; v[3] = (bf16)vreg[3][i];
            *(bf16x4*)&Bs[p][(1 + tl + 32 * i) * LDBL + f0] = v;
        }
        if (tid < 32) Bs[p][tid] = (bf16)rz;
    };
    loadA(0); loadB(0); writeA(0); writeB(0);
    __syncthreads();
    int p = 0;
    for (int ks = 0; ks < 32; ++ks) {
        if (ks + 1 < 32) { loadA(ks + 1); loadB(ks + 1); }
        bf16x8 af[8], blv[2], bhv[2];
        #pragma unroll
        for (int mi = 0; mi < 8; ++mi)
            af[mi] = *(const bf16x8*)&As[p][(mi * 16 + (l & 15)) * LDBL + (l >> 4) * 8];
        #pragma unroll
        for (int ni = 0; ni < 2; ++ni) {
            const int rb = nbase + ni * 16 + (l & 15);
            bhv[ni] = *(const bf16x8*)&Bs[p][rb * LDBL + (l >> 4) * 8];
            blv[ni] = *(const bf16x8*)&Bs[p][(rb + 1) * LDBL + (l >> 4) * 8];
        }
        #pragma unroll
        for (int ni = 0; ni < 2; ++ni)
            #pragma unroll
            for (int mi = 0; mi < 4; ++mi) {
                acc[mi][ni] = __builtin_amdgcn_mfma_f32_16x16x32_bf16(af[mi], blv[ni], acc[mi][ni], 0, 0, 0);
                acc[mi + 4][ni] = __builtin_amdgcn_mfma_f32_16x16x32_bf16(af[mi + 4], bhv[ni], acc[mi + 4][ni], 0, 0, 0);
            }
        if (ks + 1 < 32) { writeA(p ^ 1); writeB(p ^ 1); }
        __syncthreads();
        p ^= 1;
    }
    const float inv = 1.0f / 1024.0f;
    float* ob = out + (size_t)b * OUT_LEN;
    const float* acb = acv + (size_t)b * T_SZ;
    #pragma unroll
    for (int ni = 0; ni < 2; ++ni) {
        const int tt = t0 + nbase + ni * 16 + (l & 15);
        if (tt <= T_SZ) {
            float acs = 0.f;
            if (tt < T_SZ) acs += acb[tt];
            if (tt >= 1)   acs += acb[tt - 1];
            #pragma unroll
            for (int mi = 0; mi < 4; ++mi) {
                const int jl = j0 + mi * 16 + (l >> 4) * 4;
                f32x4 v;
                #pragma unroll
                for (int rr = 0; rr < 4; ++rr)
                    v[rr] = (acc[mi][ni][rr] + acc[mi + 4][ni][rr] + acs) * inv;
                __builtin_nontemporal_store(v, (f32x4*)&ob[(size_t)tt * HOP + jl]);
            }
        }
    }
}

extern "C" void kernel_launch(void* const* d_in, const int* in_sizes, int n_in,
                              void* d_out, int out_size, void* d_ws, size_t ws_size,
                              hipStream_t stream) {
    const float* magn  = (const float*)d_in[0];
    const float* phase = (const float*)d_in[1];
    const float* ac    = (const float*)d_in[2];
    const float* rk    = (const float*)d_in[3];
    const float* ik    = (const float*)d_in[4];
    float* out = (float*)d_out;

    if (ws_size >= WS_NEED) {
        bf16* Xw = (bf16*)d_ws;
        bf16* Wt = Xw + XW_ELEMS;
        cvt_w<<<512, 256, 0, stream>>>(rk, ik, Wt);
        cvt_x<<<8192, 256, 0, stream>>>(magn, phase, Xw);
        istft_gemmY<<<1088, 512, 0, stream>>>(Xw, Wt, ac, out);
    } else {
        istft_fused_legacy<<<528 * 8, 256, 0, stream>>>(magn, phase, ac, rk, ik, out);
    }
}